// Round 9
// baseline (3930.174 us; speedup 1.0000x reference)
//
#include <hip/hip_runtime.h>
#include <hip/hip_bf16.h>

typedef __bf16 bf16x8 __attribute__((ext_vector_type(8)));
typedef float  f32x4  __attribute__((ext_vector_type(4)));
typedef unsigned int u32x4 __attribute__((ext_vector_type(4)));

#define Tn 512
#define Bn 64
#define En 256
#define Hn 512
#define Ln 64

// ---- ws layout (bytes) ----
// 0     : per-WG step flags, 32 x 64 B  (dir*16 + w)
// 20480 : crf per-batch out (64 f32)
// 32768 : xfrag  [T][4][8][64][8]  bf16  (16 MiB)
// next  : hffrag [T][4][16][64][8] bf16  (32 MiB)   (64 KiB per t)
// next  : hbfrag (32 MiB)
// next  : em [T][B][L] f32 (8.39 MiB) — OVERLAPPED with wfrag (6 MiB):
//         wfrag consumed by lstm_rec, em written by fc_em afterwards.
#define FLG_STRIDE 16              // ints -> 64 B
#define CRF_OFF  20480
#define XF_OFF   32768
#define XF_BYTES (Tn*4*8*64*8*2)
#define HF_OFF   (XF_OFF + XF_BYTES)
#define HF_BYTES (Tn*4*16*64*8*2)
#define HB_OFF   (HF_OFF + HF_BYTES)
#define EM_OFF   (HB_OFF + HF_BYTES)
#define WF_OFF   EM_OFF
#define HT_BYTES 65536             // h bytes per timestep (4*16*64*8*2)

__device__ __forceinline__ float sigm_f(float x) {
  x = fminf(fmaxf(x, -30.f), 30.f);
  return 1.f / (1.f + __expf(-x));
}
__device__ __forceinline__ float tanh_f(float x) {
  x = fminf(fmaxf(x, -15.f), 15.f);
  float e = __expf(2.f * x);
  return (e - 1.f) / (e + 1.f);
}

// Device-coherent (MALL) write-through 16B store — publishes h. [R6-proven]
__device__ __forceinline__ void st_cohx4(__bf16* p, u32x4 v) {
  asm volatile("global_store_dwordx4 %0, %1, off sc0 sc1" :: "v"(p), "v"(v) : "memory");
}
// Device-coherent flag ops: sc0 sc1 ONLY (sc0-only reads stale L1 — R5). [R6-proven]
__device__ __forceinline__ int ld_flag1(const int* p) {
  int r;
  asm volatile("global_load_dword %0, %1, off sc0 sc1\n\ts_waitcnt vmcnt(0)"
               : "=v"(r) : "v"(p) : "memory");
  return r;
}
__device__ __forceinline__ void st_flag(int* p, int v) {
  asm volatile("global_store_dword %0, %1, off sc0 sc1" :: "v"(p), "v"(v) : "memory");
}

// Repack sentences (B,T,E) f32 -> bf16 MFMA A-fragment layout [t][mt][kt][lane][8]
__global__ void prep_xfrag(const float* __restrict__ x, __bf16* __restrict__ xf) {
  int idx  = blockIdx.x * 256 + threadIdx.x;   // 0 .. 1048575
  int lane = idx & 63;
  int kt   = (idx >> 6) & 7;
  int mt   = (idx >> 9) & 3;
  int t    = idx >> 11;
  int b = 16 * mt + (lane & 15);
  int k = 32 * kt + 8 * (lane >> 4);
  const float4* s = reinterpret_cast<const float4*>(x + ((size_t)b * Tn + t) * En + k);
  float4 f0 = s[0], f1 = s[1];
  bf16x8 v;
  v[0]=(__bf16)f0.x; v[1]=(__bf16)f0.y; v[2]=(__bf16)f0.z; v[3]=(__bf16)f0.w;
  v[4]=(__bf16)f1.x; v[5]=(__bf16)f1.y; v[6]=(__bf16)f1.z; v[7]=(__bf16)f1.w;
  reinterpret_cast<bf16x8*>(xf)[idx] = v;
}

// Pre-pack LSTM weights (f32) -> bf16 MFMA B-fragments:
// wf[((dir*128 + nb)*24 + kt)][lane][8]; col = 16-col block nb, gates [i f g o] interleaved.
__global__ void prep_wfrag(const float* __restrict__ w_ih_f, const float* __restrict__ w_hh_f,
                           const float* __restrict__ w_ih_b, const float* __restrict__ w_hh_b,
                           __bf16* __restrict__ wf) {
  int idx = blockIdx.x * 256 + threadIdx.x;    // 0 .. 393215
  int lane = idx & 63;
  int kt   = (idx >> 6) % 24;
  int rest = (idx >> 6) / 24;                  // dir*128 + nb
  int nb  = rest & 127;
  int dir = rest >> 7;
  const float* w_ih = dir ? w_ih_b : w_ih_f;
  const float* w_hh = dir ? w_hh_b : w_hh_f;
  int lrow = lane & 15;
  int grow = (lrow & 3) * Hn + 4 * nb + (lrow >> 2);
  int k = 32 * kt + 8 * (lane >> 4);
  const float4* src = reinterpret_cast<const float4*>(
      (k < En) ? (w_ih + (size_t)grow * En + k)
               : (w_hh + (size_t)grow * Hn + (k - En)));
  float4 f0 = src[0], f1 = src[1];
  bf16x8 v;
  v[0]=(__bf16)f0.x; v[1]=(__bf16)f0.y; v[2]=(__bf16)f0.z; v[3]=(__bf16)f0.w;
  v[4]=(__bf16)f1.x; v[5]=(__bf16)f1.y; v[6]=(__bf16)f1.z; v[7]=(__bf16)f1.w;
  reinterpret_cast<bf16x8*>(wf)[idx] = v;
}

// Persistent bidirectional LSTM, CONSOLIDATED: 32 WGs x 512 threads.
// blockIdx>>4 = dir, &15 = w (32 hidden units per WG; kt == w in the h layout).
// 8 waves: mp=wv>>2 (batch half), npp=wv&3 (32-col group). Per step:
//   poll 16 per-WG flags (1 sc0sc1 load) -> cooperative 64KB h stage into LDS ->
//   barrier -> LDS frags + 64 MFMAs -> gates via LDS transpose ->
//   publish 4KB h slice (sc0sc1) -> per-wave drain -> barrier -> tid0 posts flag.
__launch_bounds__(512, 1)
__global__ void lstm_rec(const __bf16* __restrict__ wfrag,
                         const float* __restrict__ b_ih_f, const float* __restrict__ b_hh_f,
                         const float* __restrict__ b_ih_b, const float* __restrict__ b_hh_b,
                         const __bf16* __restrict__ xfrag,
                         __bf16* __restrict__ hff, __bf16* __restrict__ hbf,
                         int* __restrict__ flags) {
  __shared__ __align__(16) char  hbuf[HT_BYTES];          // 64 KiB: h[t-1], frag layout
  __shared__ __align__(16) float lds_t[8][2][2][4][68];   // 69.6 KiB transpose buf
  __shared__ __align__(16) __bf16 lds_h[8][2][16][8];     // 4 KiB h-store staging
  const int tid  = threadIdx.x;
  const int lane = tid & 63;
  const int wv   = tid >> 6;                   // 0..7
  const int mp  = wv >> 2, npp = wv & 3;
  const int dir = blockIdx.x >> 4;
  const int w   = blockIdx.x & 15;
  const float* bi = dir ? b_ih_b : b_ih_f;
  const float* bh = dir ? b_hh_b : b_hh_f;
  __bf16* hfr = dir ? hbf : hff;
  int* fbase = flags + (size_t)dir * 16 * FLG_STRIDE;
  const int lrow = lane & 15, lhalf = lane >> 4, q = lane & 3;

  // ---- register-resident bf16 B fragments + bias
  bf16x8 Bf[2][24];
  float bias[2];
  const bf16x8* wfv = reinterpret_cast<const bf16x8*>(wfrag);
#pragma unroll
  for (int ni = 0; ni < 2; ++ni) {
    int nb = 8 * w + 2 * npp + ni;
    int grow = (lrow & 3) * Hn + 4 * nb + (lrow >> 2);
    bias[ni] = bi[grow] + bh[grow];
    size_t base = ((size_t)(dir * 128 + nb) * 24) * 64;
#pragma unroll
    for (int kt = 0; kt < 24; ++kt)
      Bf[ni][kt] = wfv[base + (size_t)kt * 64 + lane];
  }

  const f32x4 vzero = {0.f, 0.f, 0.f, 0.f};
  f32x4 acc[2][2];
  float cst[2][2];
#pragma unroll
  for (int mi = 0; mi < 2; ++mi)
#pragma unroll
    for (int ni = 0; ni < 2; ++ni) { acc[mi][ni] = vzero; cst[mi][ni] = 0.f; }

  auto xpart = [&](int tx) {   // x @ W_ih^T — independent of h
#pragma unroll
    for (int kt = 0; kt < 8; ++kt) {
      bf16x8 A0 = reinterpret_cast<const bf16x8*>(xfrag)[(((size_t)tx*4 + 2*mp+0)*8 + kt)*64 + lane];
      bf16x8 A1 = reinterpret_cast<const bf16x8*>(xfrag)[(((size_t)tx*4 + 2*mp+1)*8 + kt)*64 + lane];
      acc[0][0] = __builtin_amdgcn_mfma_f32_16x16x32_bf16(A0, Bf[0][kt], acc[0][0], 0,0,0);
      acc[0][1] = __builtin_amdgcn_mfma_f32_16x16x32_bf16(A0, Bf[1][kt], acc[0][1], 0,0,0);
      acc[1][0] = __builtin_amdgcn_mfma_f32_16x16x32_bf16(A1, Bf[0][kt], acc[1][0], 0,0,0);
      acc[1][1] = __builtin_amdgcn_mfma_f32_16x16x32_bf16(A1, Bf[1][kt], acc[1][1], 0,0,0);
    }
  };

  xpart(dir ? (Tn - 1) : 0);

  for (int s = 0; s < Tn; ++s) {
    const int t = dir ? (Tn - 1 - s) : s;
    if (s > 0) {
      {  // ---- poll: 16 per-WG flags of this dir, one sc0sc1 load (MALL-fresh)
        const int* fl = fbase + (size_t)(lane & 15) * FLG_STRIDE;
        int guard = 0;
        for (;;) {
          int f = ld_flag1(fl);
          if (__all(f >= s)) break;
          if (++guard > (1 << 15)) break;     // fail fast (wrong answer), never hang
          __builtin_amdgcn_s_sleep(1);
        }
      }
      __builtin_amdgcn_sched_barrier(0);
      const int tprev = dir ? (t + 1) : (t - 1);
      // ---- cooperative stage of full h[t-1] (64 KiB) into LDS (linear copy) ----
      const char* gsrc = (const char*)hfr + (size_t)tprev * HT_BYTES;
      const int cbase = wv * 8192 + lane * 16;
      u32x4 tmp[8];
#pragma unroll
      for (int j = 0; j < 8; ++j)
        tmp[j] = *reinterpret_cast<const u32x4*>(gsrc + cbase + j * 1024);
#pragma unroll
      for (int j = 0; j < 8; ++j)
        *reinterpret_cast<u32x4*>(hbuf + cbase + j * 1024) = tmp[j];
      __syncthreads();
      // ---- h fragments from LDS + h-part MFMAs ----
#pragma unroll
      for (int kt = 0; kt < 16; ++kt) {
        bf16x8 A0 = *reinterpret_cast<const bf16x8*>(hbuf + (((2*mp+0)*16 + kt)*64 + lane)*16);
        bf16x8 A1 = *reinterpret_cast<const bf16x8*>(hbuf + (((2*mp+1)*16 + kt)*64 + lane)*16);
        acc[0][0] = __builtin_amdgcn_mfma_f32_16x16x32_bf16(A0, Bf[0][8+kt], acc[0][0], 0,0,0);
        acc[0][1] = __builtin_amdgcn_mfma_f32_16x16x32_bf16(A0, Bf[1][8+kt], acc[0][1], 0,0,0);
        acc[1][0] = __builtin_amdgcn_mfma_f32_16x16x32_bf16(A1, Bf[0][8+kt], acc[1][0], 0,0,0);
        acc[1][1] = __builtin_amdgcn_mfma_f32_16x16x32_bf16(A1, Bf[1][8+kt], acc[1][1], 0,0,0);
      }
    }
    // ---- activations (each lane its own gate), shared via LDS transpose ----
#pragma unroll
    for (int mi = 0; mi < 2; ++mi)
#pragma unroll
      for (int ni = 0; ni < 2; ++ni)
#pragma unroll
        for (int r = 0; r < 4; ++r) {
          float v = acc[mi][ni][r] + bias[ni];
          lds_t[wv][mi][ni][r][lane] = (q == 2) ? tanh_f(v) : sigm_f(v);
        }
    asm volatile("s_waitcnt lgkmcnt(0)" ::: "memory");
    __builtin_amdgcn_sched_barrier(0);
    // ---- each lane finishes ONE row (r==q) per (mi,ni): c,h update, stage h ----
#pragma unroll
    for (int mi = 0; mi < 2; ++mi)
#pragma unroll
      for (int ni = 0; ni < 2; ++ni) {
        const f32x4 g4 = *reinterpret_cast<const f32x4*>(&lds_t[wv][mi][ni][q][lane & 60]);
        float cc = g4[1] * cst[mi][ni] + g4[0] * g4[2];   // f*c + i*g
        cst[mi][ni] = cc;
        float hv = g4[3] * tanh_f(cc);                    // o * tanh(c)
        lds_h[wv][mi][4*lhalf + q][4*ni + (lrow >> 2)] = (__bf16)hv;
      }
    asm volatile("s_waitcnt lgkmcnt(0)" ::: "memory");
    __builtin_amdgcn_sched_barrier(0);
    // ---- coalesced 16B publication (kt == w): 32 stores per wave ----
    if (lane < 32) {
      int mi = lane >> 4, boff = lane & 15;
      u32x4 blk = *reinterpret_cast<const u32x4*>(&lds_h[wv][mi][boff][0]);
      size_t off = ((((size_t)t*4 + (2*mp+mi))*16 + w)*64 + (boff + 16*npp))*8;
      st_cohx4(hfr + off, blk);
    }
    // ---- release: each wave drains own stores; barrier; tid0 posts WG flag ----
    asm volatile("s_waitcnt vmcnt(0)" ::: "memory");
    __syncthreads();
    if (tid == 0)
      st_flag(fbase + (size_t)w * FLG_STRIDE, s + 1);
    // ---- overlap next-step x MFMAs with peers' polls/loads ----
    if (s + 1 < Tn) {
#pragma unroll
      for (int mi = 0; mi < 2; ++mi)
#pragma unroll
        for (int ni = 0; ni < 2; ++ni) acc[mi][ni] = vzero;
      xpart(dir ? (Tn - 2 - s) : (s + 1));
    }
  }
}

// emissions = [hf|hb] @ fc_w^T + fc_b, + 10000 at col 0 where labels==0. One WG per t.
__global__ void fc_em(const __bf16* __restrict__ hff, const __bf16* __restrict__ hbf,
                      const float* __restrict__ fc_w, const float* __restrict__ fc_b,
                      const int* __restrict__ labels, float* __restrict__ em) {
  __shared__ __bf16 wlds[4 * 16 * 64 * 8];   // 64 KiB: half-K of fc_w^T fragments
  const int tid = threadIdx.x, lane = tid & 63, wv = tid >> 6;
  const int mp = wv >> 1, np = wv & 1;
  const int t = blockIdx.x;
  const f32x4 vzero = {0.f, 0.f, 0.f, 0.f};
  f32x4 acc[2][2];
#pragma unroll
  for (int mi = 0; mi < 2; ++mi)
#pragma unroll
    for (int ni = 0; ni < 2; ++ni) acc[mi][ni] = vzero;

  for (int kh = 0; kh < 2; ++kh) {
    __syncthreads();
#pragma unroll
    for (int r = 0; r < 16; ++r) {
      int fidx = r * 256 + tid;
      int lane2 = fidx & 63, ktl = (fidx >> 6) & 15, nt = fidx >> 10;
      int col = 16 * nt + (lane2 & 15);
      int k = 32 * (16 * kh + ktl) + 8 * (lane2 >> 4);
      const float4* src = reinterpret_cast<const float4*>(fc_w + (size_t)col * 1024 + k);
      float4 f0 = src[0], f1 = src[1];
      bf16x8 v;
      v[0]=(__bf16)f0.x; v[1]=(__bf16)f0.y; v[2]=(__bf16)f0.z; v[3]=(__bf16)f0.w;
      v[4]=(__bf16)f1.x; v[5]=(__bf16)f1.y; v[6]=(__bf16)f1.z; v[7]=(__bf16)f1.w;
      reinterpret_cast<bf16x8*>(wlds)[fidx] = v;
    }
    __syncthreads();
#pragma unroll
    for (int ktl = 0; ktl < 16; ++ktl) {
      int KT = 16 * kh + ktl;
      const __bf16* hsrc = (KT < 16) ? hff : hbf;
      int kti = KT & 15;
      bf16x8 A0 = reinterpret_cast<const bf16x8*>(hsrc)[(((size_t)t*4 + 2*mp+0)*16 + kti)*64 + lane];
      bf16x8 A1 = reinterpret_cast<const bf16x8*>(hsrc)[(((size_t)t*4 + 2*mp+1)*16 + kti)*64 + lane];
      bf16x8 B0 = reinterpret_cast<const bf16x8*>(wlds)[((2*np+0)*16 + ktl)*64 + lane];
      bf16x8 B1 = reinterpret_cast<const bf16x8*>(wlds)[((2*np+1)*16 + ktl)*64 + lane];
      acc[0][0] = __builtin_amdgcn_mfma_f32_16x16x32_bf16(A0, B0, acc[0][0], 0,0,0);
      acc[0][1] = __builtin_amdgcn_mfma_f32_16x16x32_bf16(A0, B1, acc[0][1], 0,0,0);
      acc[1][0] = __builtin_amdgcn_mfma_f32_16x16x32_bf16(A1, B0, acc[1][0], 0,0,0);
      acc[1][1] = __builtin_amdgcn_mfma_f32_16x16x32_bf16(A1, B1, acc[1][1], 0,0,0);
    }
  }
#pragma unroll
  for (int mi = 0; mi < 2; ++mi)
#pragma unroll
    for (int ni = 0; ni < 2; ++ni) {
      int col = 32*np + 16*ni + (lane & 15);
      float fb = fc_b[col];
#pragma unroll
      for (int r = 0; r < 4; ++r) {
        int b = 16*(2*mp+mi) + 4*(lane>>4) + r;
        float v = acc[mi][ni][r] + fb;
        if (col == 0) {
          if (labels[(size_t)b * Tn + t] == 0) v += 10000.f;
        }
        em[((size_t)t * 64 + b) * 64 + col] = v;
      }
    }
}

// CRF NLL per batch (one WG per b): gold score (parallel over t) + forward logsumexp
// recursion (sequential t; 64 labels = 16 j/wave, 4-lane quads split the i-sum).
__global__ void crf_k(const float* __restrict__ em, const int* __restrict__ labels,
                      const float* __restrict__ c_start, const float* __restrict__ c_end,
                      const float* __restrict__ c_trans, float* __restrict__ out_b) {
  __shared__ float s_trans[64][65];
  __shared__ float s_alpha[64];
  __shared__ float s_p[4];
  __shared__ int   s_c[4];
  __shared__ float s_score;
  const int b = blockIdx.x, tid = threadIdx.x;

  for (int i = tid; i < 4096; i += 256) s_trans[i >> 6][i & 63] = c_trans[i];
  if (tid < 64) s_alpha[tid] = c_start[tid] + em[(size_t)b * 64 + tid];
  __syncthreads();

  float part = 0.f; int cntm = 0;
  for (int t = tid; t < Tn; t += 256) {
    int lab = labels[(size_t)b * Tn + t];
    cntm += (lab != 0);
    if (t >= 1 && lab != 0) {
      int lp = labels[(size_t)b * Tn + t - 1];
      part += s_trans[lp][lab] + em[((size_t)t * 64 + b) * 64 + lab];
    }
  }
  for (int off = 1; off < 64; off <<= 1) {
    part += __shfl_xor(part, off);
    cntm += __shfl_xor(cntm, off);
  }
  if ((tid & 63) == 0) { s_p[tid >> 6] = part; s_c[tid >> 6] = cntm; }
  __syncthreads();
  if (tid == 0) {
    float sp = s_p[0] + s_p[1] + s_p[2] + s_p[3];
    int   sc = s_c[0] + s_c[1] + s_c[2] + s_c[3];
    int tag0 = labels[(size_t)b * Tn];
    float score = c_start[tag0] + em[(size_t)b * 64 + tag0] + sp;
    int last_tag = labels[(size_t)b * Tn + (sc - 1)];
    score += c_end[last_tag];
    s_score = score;
  }
  __syncthreads();

  const int wv2 = tid >> 6, lane = tid & 63;
  const int j  = 16 * wv2 + (lane >> 2);
  const int i0 = 16 * (lane & 3);
  for (int t = 1; t < Tn; ++t) {
    int lab = labels[(size_t)b * Tn + t];
    if (lab != 0) {
      float em_tj = em[((size_t)t * 64 + b) * 64 + j];
      float av[16]; float m = -3.0e38f;
#pragma unroll
      for (int ii = 0; ii < 16; ++ii) {
        float a = s_alpha[i0 + ii] + s_trans[i0 + ii][j];
        av[ii] = a; m = fmaxf(m, a);
      }
      float ss = 0.f;
#pragma unroll
      for (int ii = 0; ii < 16; ++ii) ss += __expf(av[ii] - m);
      float m1 = __shfl_xor(m, 1), s1 = __shfl_xor(ss, 1);
      float M = fmaxf(m, m1); ss = ss * __expf(m - M) + s1 * __expf(m1 - M); m = M;
      m1 = __shfl_xor(m, 2); s1 = __shfl_xor(ss, 2);
      M = fmaxf(m, m1); ss = ss * __expf(m - M) + s1 * __expf(m1 - M); m = M;
      float nxt = em_tj + m + __logf(ss);
      __syncthreads();
      if ((lane & 3) == 0) s_alpha[j] = nxt;
      __syncthreads();
    }
  }
  __syncthreads();
  if (tid < 64) {
    float v = s_alpha[tid] + c_end[tid];
    float m = v;
    for (int off = 1; off < 64; off <<= 1) m = fmaxf(m, __shfl_xor(m, off));
    float ssum = __expf(v - m);
    for (int off = 1; off < 64; off <<= 1) ssum += __shfl_xor(ssum, off);
    if (tid == 0) out_b[b] = (m + __logf(ssum)) - s_score;
  }
}

__global__ void reduce_out(const float* __restrict__ in, float* __restrict__ out) {
  float v = in[threadIdx.x];
  for (int off = 1; off < 64; off <<= 1) v += __shfl_xor(v, off);
  if (threadIdx.x == 0) out[0] = v;
}

extern "C" void kernel_launch(void* const* d_in, const int* in_sizes, int n_in,
                              void* d_out, int out_size, void* d_ws, size_t ws_size,
                              hipStream_t stream) {
  const float* sentences = (const float*)d_in[0];
  const int*   labels    = (const int*)  d_in[1];
  const float* w_ih_f    = (const float*)d_in[2];
  const float* w_hh_f    = (const float*)d_in[3];
  const float* b_ih_f    = (const float*)d_in[4];
  const float* b_hh_f    = (const float*)d_in[5];
  const float* w_ih_b    = (const float*)d_in[6];
  const float* w_hh_b    = (const float*)d_in[7];
  const float* b_ih_b    = (const float*)d_in[8];
  const float* b_hh_b    = (const float*)d_in[9];
  const float* fc_w      = (const float*)d_in[10];
  const float* fc_b      = (const float*)d_in[11];
  const float* c_start   = (const float*)d_in[12];
  const float* c_end     = (const float*)d_in[13];
  const float* c_trans   = (const float*)d_in[14];

  char* ws = (char*)d_ws;
  int*    flags     = (int*)ws;
  float*  crf_out   = (float*)(ws + CRF_OFF);
  __bf16* xfrag     = (__bf16*)(ws + XF_OFF);
  __bf16* hff       = (__bf16*)(ws + HF_OFF);
  __bf16* hbf       = (__bf16*)(ws + HB_OFF);
  float*  em        = (float*)(ws + EM_OFF);
  __bf16* wfrag     = (__bf16*)(ws + WF_OFF);  // overlaps em (consumed before em written)

  hipMemsetAsync(d_ws, 0, 16384, stream);      // reset per-WG flags each replay
  prep_xfrag<<<4096, 256, 0, stream>>>(sentences, xfrag);
  prep_wfrag<<<1536, 256, 0, stream>>>(w_ih_f, w_hh_f, w_ih_b, w_hh_b, wfrag);
  lstm_rec<<<32, 512, 0, stream>>>(wfrag, b_ih_f, b_hh_f, b_ih_b, b_hh_b,
                                   xfrag, hff, hbf, flags);
  fc_em<<<512, 256, 0, stream>>>(hff, hbf, fc_w, fc_b, labels, em);
  crf_k<<<64, 256, 0, stream>>>(em, labels, c_start, c_end, c_trans, crf_out);
  reduce_out<<<1, 64, 0, stream>>>(crf_out, (float*)d_out);
}

// Round 10
// 2968.579 us; speedup vs baseline: 1.3239x; 1.3239x over previous
//
#include <hip/hip_runtime.h>
#include <hip/hip_bf16.h>

typedef __bf16 bf16x8 __attribute__((ext_vector_type(8)));
typedef float  f32x4  __attribute__((ext_vector_type(4)));
typedef unsigned int u32x4 __attribute__((ext_vector_type(4)));

#define Tn 512
#define Bn 64
#define En 256
#define Hn 512
#define Ln 64

// Sentinel: bf16 NaN pair per dword. h = o*tanh(c) is finite => data can never
// equal this. A 16B block whose first dword != SENT has been written.
#define SENT 0x7FC17FC1u

// ---- ws layout (bytes) ----
// 20480 : crf per-batch out (64 f32)
// 32768 : xfrag  [T][4][8][64][8]  bf16  (16 MiB)
// next  : hffrag [T][4][16][64][8] bf16  (32 MiB)
// next  : hbfrag (32 MiB)
// next  : em [T][B][L] f32 (8.39 MiB) — OVERLAPPED with wfrag (6 MiB):
//         wfrag consumed by lstm_rec, em written by fc_em afterwards.
#define CRF_OFF  20480
#define XF_OFF   32768
#define XF_BYTES (Tn*4*8*64*8*2)
#define HF_OFF   (XF_OFF + XF_BYTES)
#define HF_BYTES (Tn*4*16*64*8*2)
#define HB_OFF   (HF_OFF + HF_BYTES)
#define EM_OFF   (HB_OFF + HF_BYTES)
#define WF_OFF   EM_OFF

__device__ __forceinline__ float sigm_f(float x) {
  x = fminf(fmaxf(x, -30.f), 30.f);
  return 1.f / (1.f + __expf(-x));
}
__device__ __forceinline__ float tanh_f(float x) {
  x = fminf(fmaxf(x, -15.f), 15.f);
  float e = __expf(2.f * x);
  return (e - 1.f) / (e + 1.f);
}

// Device-coherent (MALL) write-through 16B store. [R6-proven]
__device__ __forceinline__ void st_cohx4(__bf16* p, u32x4 v) {
  asm volatile("global_store_dwordx4 %0, %1, off sc0 sc1" :: "v"(p), "v"(v) : "memory");
}
// Device-coherent (MALL-fresh) 16B load — required for the retry poll: plain/sc0
// loads can cache the sentinel in L1/L2 and spin forever (R5 lesson).
__device__ __forceinline__ bf16x8 ld_cohx8(const __bf16* p) {
  u32x4 r;
  asm volatile("global_load_dwordx4 %0, %1, off sc0 sc1" : "=v"(r) : "v"(p));
  return __builtin_bit_cast(bf16x8, r);
}

// Pre-fill both h buffers with the sentinel pattern (MALL write-through so the
// sc0sc1 pollers see it). 4096 blocks x 256 thr x 4 blocks = 4 Mi x 16 B = 64 MiB.
__global__ void fill_sent(__bf16* __restrict__ h) {
  const u32x4 S = {SENT, SENT, SENT, SENT};
  size_t gid = (size_t)blockIdx.x * 256 + threadIdx.x;
#pragma unroll
  for (int j = 0; j < 4; ++j)
    st_cohx4(h + (gid + (size_t)j * 1048576) * 8, S);
}

// Repack sentences (B,T,E) f32 -> bf16 MFMA A-fragment layout [t][mt][kt][lane][8]
__global__ void prep_xfrag(const float* __restrict__ x, __bf16* __restrict__ xf) {
  int idx  = blockIdx.x * 256 + threadIdx.x;   // 0 .. 1048575
  int lane = idx & 63;
  int kt   = (idx >> 6) & 7;
  int mt   = (idx >> 9) & 3;
  int t    = idx >> 11;
  int b = 16 * mt + (lane & 15);
  int k = 32 * kt + 8 * (lane >> 4);
  const float4* s = reinterpret_cast<const float4*>(x + ((size_t)b * Tn + t) * En + k);
  float4 f0 = s[0], f1 = s[1];
  bf16x8 v;
  v[0]=(__bf16)f0.x; v[1]=(__bf16)f0.y; v[2]=(__bf16)f0.z; v[3]=(__bf16)f0.w;
  v[4]=(__bf16)f1.x; v[5]=(__bf16)f1.y; v[6]=(__bf16)f1.z; v[7]=(__bf16)f1.w;
  reinterpret_cast<bf16x8*>(xf)[idx] = v;
}

// Pre-pack LSTM weights (f32) into bf16 MFMA B-fragments:
// wf[((dir*32+wu)*4+nq)*24+kt][lane][8]; col=16*nq+lrow, gates interleaved [i f g o].
__global__ void prep_wfrag(const float* __restrict__ w_ih_f, const float* __restrict__ w_hh_f,
                           const float* __restrict__ w_ih_b, const float* __restrict__ w_hh_b,
                           __bf16* __restrict__ wf) {
  int idx = blockIdx.x * 256 + threadIdx.x;    // 0 .. 393215
  int lane = idx & 63;
  int kt   = (idx >> 6) % 24;
  int rest = (idx >> 6) / 24;                  // (dir*32+wu)*4+nq
  int nq  = rest & 3;
  int wu  = (rest >> 2) & 31;
  int dir = rest >> 7;
  const float* w_ih = dir ? w_ih_b : w_ih_f;
  const float* w_hh = dir ? w_hh_b : w_hh_f;
  int col  = 16 * nq + (lane & 15);
  int grow = (col & 3) * Hn + (wu * 16 + (col >> 2));
  int k = 32 * kt + 8 * (lane >> 4);
  const float4* src = reinterpret_cast<const float4*>(
      (k < En) ? (w_ih + (size_t)grow * En + k)
               : (w_hh + (size_t)grow * Hn + (k - En)));
  float4 f0 = src[0], f1 = src[1];
  bf16x8 v;
  v[0]=(__bf16)f0.x; v[1]=(__bf16)f0.y; v[2]=(__bf16)f0.z; v[3]=(__bf16)f0.w;
  v[4]=(__bf16)f1.x; v[5]=(__bf16)f1.y; v[6]=(__bf16)f1.z; v[7]=(__bf16)f1.w;
  reinterpret_cast<bf16x8*>(wf)[idx] = v;
}

// Persistent bidirectional LSTM, FLAG-FREE: 64 WGs x 256 thr (R6 shape — keeps
// weights register-resident). Sync = the data itself: h buffers pre-filled with
// NaN sentinel; producers publish via sc0sc1 stores and continue (no drain, no
// flag); consumers retry-load their 32 blocks (sc0sc1) until no block reads
// sentinel. Waves self-synchronize through the data web.
__launch_bounds__(256, 1)
__global__ void lstm_rec(const __bf16* __restrict__ wfrag,
                         const float* __restrict__ b_ih_f, const float* __restrict__ b_hh_f,
                         const float* __restrict__ b_ih_b, const float* __restrict__ b_hh_b,
                         const __bf16* __restrict__ xfrag,
                         __bf16* __restrict__ hff, __bf16* __restrict__ hbf) {
  __shared__ __align__(16) float  lds_t[4][2][2][4][68];  // padded transpose buf
  __shared__ __align__(16) __bf16 lds_h[4][2][16][8];
  const int tid  = threadIdx.x;
  const int lane = tid & 63;
  const int wv   = tid >> 6;
  const int mp = wv >> 1, np = wv & 1;
  const int dir = blockIdx.x >> 5;
  const int wu  = blockIdx.x & 31;
  const float* bi = dir ? b_ih_b : b_ih_f;
  const float* bh = dir ? b_hh_b : b_hh_f;
  __bf16* hfr = dir ? hbf : hff;
  const int lrow = lane & 15, lhalf = lane >> 4, q = lane & 3;

  // ---- register-resident bf16 B fragments + bias
  bf16x8 Bf[2][24];
  float bias[2];
  const bf16x8* wfv = reinterpret_cast<const bf16x8*>(wfrag);
#pragma unroll
  for (int ni = 0; ni < 2; ++ni) {
    int col  = 32 * np + 16 * ni + lrow;
    int grow = (col & 3) * Hn + (wu * 16 + (col >> 2));
    bias[ni] = bi[grow] + bh[grow];
    int nq = 2 * np + ni;
    size_t base = ((((size_t)dir * 32 + wu) * 4 + nq) * 24) * 64;
#pragma unroll
    for (int kt = 0; kt < 24; ++kt)
      Bf[ni][kt] = wfv[base + (size_t)kt * 64 + lane];
  }

  const f32x4 vzero = {0.f, 0.f, 0.f, 0.f};
  f32x4 acc[2][2];
  float cst[2][2];
#pragma unroll
  for (int mi = 0; mi < 2; ++mi)
#pragma unroll
    for (int ni = 0; ni < 2; ++ni) { acc[mi][ni] = vzero; cst[mi][ni] = 0.f; }

  auto xpart = [&](int tx) {   // x @ W_ih^T — independent of h
#pragma unroll
    for (int kt = 0; kt < 8; ++kt) {
      bf16x8 A0 = reinterpret_cast<const bf16x8*>(xfrag)[(((size_t)tx*4 + 2*mp+0)*8 + kt)*64 + lane];
      bf16x8 A1 = reinterpret_cast<const bf16x8*>(xfrag)[(((size_t)tx*4 + 2*mp+1)*8 + kt)*64 + lane];
      acc[0][0] = __builtin_amdgcn_mfma_f32_16x16x32_bf16(A0, Bf[0][kt], acc[0][0], 0,0,0);
      acc[0][1] = __builtin_amdgcn_mfma_f32_16x16x32_bf16(A0, Bf[1][kt], acc[0][1], 0,0,0);
      acc[1][0] = __builtin_amdgcn_mfma_f32_16x16x32_bf16(A1, Bf[0][kt], acc[1][0], 0,0,0);
      acc[1][1] = __builtin_amdgcn_mfma_f32_16x16x32_bf16(A1, Bf[1][kt], acc[1][1], 0,0,0);
    }
  };

  xpart(dir ? (Tn - 1) : 0);

  for (int s = 0; s < Tn; ++s) {
    const int t = dir ? (Tn - 1 - s) : s;
    if (s > 0) {
      const int tprev = dir ? (t + 1) : (t - 1);
      const __bf16* b0 = hfr + ((((size_t)tprev*4 + 2*mp+0)*16)*64 + lane)*8;
      const __bf16* b1 = hfr + ((((size_t)tprev*4 + 2*mp+1)*16)*64 + lane)*8;
      // ---- data-poll: load 32 blocks MALL-fresh; retry batch until none is SENT
      bf16x8 HA[2][16];
      int guard = 0;
      for (;;) {
#pragma unroll
        for (int kt = 0; kt < 16; ++kt) HA[0][kt] = ld_cohx8(b0 + kt * 512);
#pragma unroll
        for (int kt = 0; kt < 16; ++kt) HA[1][kt] = ld_cohx8(b1 + kt * 512);
        asm volatile("s_waitcnt vmcnt(0)" ::: "memory");
        unsigned ok = 1u;
#pragma unroll
        for (int mi = 0; mi < 2; ++mi)
#pragma unroll
          for (int kt = 0; kt < 16; ++kt) {
            u32x4 u = __builtin_bit_cast(u32x4, HA[mi][kt]);
            ok &= (u[0] != SENT) ? 1u : 0u;
          }
        if (__all(ok != 0u)) break;
        if (++guard > 512) break;             // fail fast (wrong answer), never hang
        __builtin_amdgcn_s_sleep(1);
      }
      __builtin_amdgcn_sched_barrier(0);
#pragma unroll
      for (int kt = 0; kt < 16; ++kt) {
        acc[0][0] = __builtin_amdgcn_mfma_f32_16x16x32_bf16(HA[0][kt], Bf[0][8+kt], acc[0][0], 0,0,0);
        acc[0][1] = __builtin_amdgcn_mfma_f32_16x16x32_bf16(HA[0][kt], Bf[1][8+kt], acc[0][1], 0,0,0);
        acc[1][0] = __builtin_amdgcn_mfma_f32_16x16x32_bf16(HA[1][kt], Bf[0][8+kt], acc[1][0], 0,0,0);
        acc[1][1] = __builtin_amdgcn_mfma_f32_16x16x32_bf16(HA[1][kt], Bf[1][8+kt], acc[1][1], 0,0,0);
      }
    }
    // ---- activations (each lane its own gate), shared via LDS transpose ----
#pragma unroll
    for (int mi = 0; mi < 2; ++mi)
#pragma unroll
      for (int ni = 0; ni < 2; ++ni)
#pragma unroll
        for (int r = 0; r < 4; ++r) {
          float v = acc[mi][ni][r] + bias[ni];
          lds_t[wv][mi][ni][r][lane] = (q == 2) ? tanh_f(v) : sigm_f(v);
        }
    asm volatile("s_waitcnt lgkmcnt(0)" ::: "memory");
    __builtin_amdgcn_sched_barrier(0);
    // ---- each lane finishes ONE row (r==q) per (mi,ni): c,h update, stage h ----
#pragma unroll
    for (int mi = 0; mi < 2; ++mi)
#pragma unroll
      for (int ni = 0; ni < 2; ++ni) {
        const f32x4 g4 = *reinterpret_cast<const f32x4*>(&lds_t[wv][mi][ni][q][lane & 60]);
        float cc = g4[1] * cst[mi][ni] + g4[0] * g4[2];   // f*c + i*g
        cst[mi][ni] = cc;
        float hv = g4[3] * tanh_f(cc);                    // o * tanh(c)
        lds_h[wv][mi][4*lhalf + q][4*ni + (lrow >> 2)] = (__bf16)hv;
      }
    asm volatile("s_waitcnt lgkmcnt(0)" ::: "memory");
    __builtin_amdgcn_sched_barrier(0);
    // ---- publish 16B blocks to MALL; NO drain, NO flag — data IS the signal ----
    if (lane < 32) {
      int mi = lane >> 4, boff = lane & 15;
      u32x4 blk = *reinterpret_cast<const u32x4*>(&lds_h[wv][mi][boff][0]);
      size_t off = ((((size_t)t*4 + (2*mp+mi))*16 + (wu>>1))*64
                    + (boff + 16*((2*wu + np) & 3)))*8;
      st_cohx4(hfr + off, blk);
    }
    // ---- overlap next-step x MFMAs with the store flight ----
    if (s + 1 < Tn) {
#pragma unroll
      for (int mi = 0; mi < 2; ++mi)
#pragma unroll
        for (int ni = 0; ni < 2; ++ni) acc[mi][ni] = vzero;
      xpart(dir ? (Tn - 2 - s) : (s + 1));
    }
  }
}

// emissions = [hf|hb] @ fc_w^T + fc_b, + 10000 at col 0 where labels==0. One WG per t.
__global__ void fc_em(const __bf16* __restrict__ hff, const __bf16* __restrict__ hbf,
                      const float* __restrict__ fc_w, const float* __restrict__ fc_b,
                      const int* __restrict__ labels, float* __restrict__ em) {
  __shared__ __bf16 wlds[4 * 16 * 64 * 8];   // 64 KiB: half-K of fc_w^T fragments
  const int tid = threadIdx.x, lane = tid & 63, wv = tid >> 6;
  const int mp = wv >> 1, np = wv & 1;
  const int t = blockIdx.x;
  const f32x4 vzero = {0.f, 0.f, 0.f, 0.f};
  f32x4 acc[2][2];
#pragma unroll
  for (int mi = 0; mi < 2; ++mi)
#pragma unroll
    for (int ni = 0; ni < 2; ++ni) acc[mi][ni] = vzero;

  for (int kh = 0; kh < 2; ++kh) {
    __syncthreads();
#pragma unroll
    for (int r = 0; r < 16; ++r) {
      int fidx = r * 256 + tid;
      int lane2 = fidx & 63, ktl = (fidx >> 6) & 15, nt = fidx >> 10;
      int col = 16 * nt + (lane2 & 15);
      int k = 32 * (16 * kh + ktl) + 8 * (lane2 >> 4);
      const float4* src = reinterpret_cast<const float4*>(fc_w + (size_t)col * 1024 + k);
      float4 f0 = src[0], f1 = src[1];
      bf16x8 v;
      v[0]=(__bf16)f0.x; v[1]=(__bf16)f0.y; v[2]=(__bf16)f0.z; v[3]=(__bf16)f0.w;
      v[4]=(__bf16)f1.x; v[5]=(__bf16)f1.y; v[6]=(__bf16)f1.z; v[7]=(__bf16)f1.w;
      reinterpret_cast<bf16x8*>(wlds)[fidx] = v;
    }
    __syncthreads();
#pragma unroll
    for (int ktl = 0; ktl < 16; ++ktl) {
      int KT = 16 * kh + ktl;
      const __bf16* hsrc = (KT < 16) ? hff : hbf;
      int kti = KT & 15;
      bf16x8 A0 = reinterpret_cast<const bf16x8*>(hsrc)[(((size_t)t*4 + 2*mp+0)*16 + kti)*64 + lane];
      bf16x8 A1 = reinterpret_cast<const bf16x8*>(hsrc)[(((size_t)t*4 + 2*mp+1)*16 + kti)*64 + lane];
      bf16x8 B0 = reinterpret_cast<const bf16x8*>(wlds)[((2*np+0)*16 + ktl)*64 + lane];
      bf16x8 B1 = reinterpret_cast<const bf16x8*>(wlds)[((2*np+1)*16 + ktl)*64 + lane];
      acc[0][0] = __builtin_amdgcn_mfma_f32_16x16x32_bf16(A0, B0, acc[0][0], 0,0,0);
      acc[0][1] = __builtin_amdgcn_mfma_f32_16x16x32_bf16(A0, B1, acc[0][1], 0,0,0);
      acc[1][0] = __builtin_amdgcn_mfma_f32_16x16x32_bf16(A1, B0, acc[1][0], 0,0,0);
      acc[1][1] = __builtin_amdgcn_mfma_f32_16x16x32_bf16(A1, B1, acc[1][1], 0,0,0);
    }
  }
#pragma unroll
  for (int mi = 0; mi < 2; ++mi)
#pragma unroll
    for (int ni = 0; ni < 2; ++ni) {
      int col = 32*np + 16*ni + (lane & 15);
      float fb = fc_b[col];
#pragma unroll
      for (int r = 0; r < 4; ++r) {
        int b = 16*(2*mp+mi) + 4*(lane>>4) + r;
        float v = acc[mi][ni][r] + fb;
        if (col == 0) {
          if (labels[(size_t)b * Tn + t] == 0) v += 10000.f;
        }
        em[((size_t)t * 64 + b) * 64 + col] = v;
      }
    }
}

// CRF NLL per batch (one WG per b): gold score (parallel over t) + forward logsumexp
// recursion (sequential t; 64 labels = 16 j/wave, 4-lane quads split the i-sum).
__global__ void crf_k(const float* __restrict__ em, const int* __restrict__ labels,
                      const float* __restrict__ c_start, const float* __restrict__ c_end,
                      const float* __restrict__ c_trans, float* __restrict__ out_b) {
  __shared__ float s_trans[64][65];
  __shared__ float s_alpha[64];
  __shared__ float s_p[4];
  __shared__ int   s_c[4];
  __shared__ float s_score;
  const int b = blockIdx.x, tid = threadIdx.x;

  for (int i = tid; i < 4096; i += 256) s_trans[i >> 6][i & 63] = c_trans[i];
  if (tid < 64) s_alpha[tid] = c_start[tid] + em[(size_t)b * 64 + tid];
  __syncthreads();

  float part = 0.f; int cntm = 0;
  for (int t = tid; t < Tn; t += 256) {
    int lab = labels[(size_t)b * Tn + t];
    cntm += (lab != 0);
    if (t >= 1 && lab != 0) {
      int lp = labels[(size_t)b * Tn + t - 1];
      part += s_trans[lp][lab] + em[((size_t)t * 64 + b) * 64 + lab];
    }
  }
  for (int off = 1; off < 64; off <<= 1) {
    part += __shfl_xor(part, off);
    cntm += __shfl_xor(cntm, off);
  }
  if ((tid & 63) == 0) { s_p[tid >> 6] = part; s_c[tid >> 6] = cntm; }
  __syncthreads();
  if (tid == 0) {
    float sp = s_p[0] + s_p[1] + s_p[2] + s_p[3];
    int   sc = s_c[0] + s_c[1] + s_c[2] + s_c[3];
    int tag0 = labels[(size_t)b * Tn];
    float score = c_start[tag0] + em[(size_t)b * 64 + tag0] + sp;
    int last_tag = labels[(size_t)b * Tn + (sc - 1)];
    score += c_end[last_tag];
    s_score = score;
  }
  __syncthreads();

  const int wv2 = tid >> 6, lane = tid & 63;
  const int j  = 16 * wv2 + (lane >> 2);
  const int i0 = 16 * (lane & 3);
  for (int t = 1; t < Tn; ++t) {
    int lab = labels[(size_t)b * Tn + t];
    if (lab != 0) {
      float em_tj = em[((size_t)t * 64 + b) * 64 + j];
      float av[16]; float m = -3.0e38f;
#pragma unroll
      for (int ii = 0; ii < 16; ++ii) {
        float a = s_alpha[i0 + ii] + s_trans[i0 + ii][j];
        av[ii] = a; m = fmaxf(m, a);
      }
      float ss = 0.f;
#pragma unroll
      for (int ii = 0; ii < 16; ++ii) ss += __expf(av[ii] - m);
      float m1 = __shfl_xor(m, 1), s1 = __shfl_xor(ss, 1);
      float M = fmaxf(m, m1); ss = ss * __expf(m - M) + s1 * __expf(m1 - M); m = M;
      m1 = __shfl_xor(m, 2); s1 = __shfl_xor(ss, 2);
      M = fmaxf(m, m1); ss = ss * __expf(m - M) + s1 * __expf(m1 - M); m = M;
      float nxt = em_tj + m + __logf(ss);
      __syncthreads();
      if ((lane & 3) == 0) s_alpha[j] = nxt;
      __syncthreads();
    }
  }
  __syncthreads();
  if (tid < 64) {
    float v = s_alpha[tid] + c_end[tid];
    float m = v;
    for (int off = 1; off < 64; off <<= 1) m = fmaxf(m, __shfl_xor(m, off));
    float ssum = __expf(v - m);
    for (int off = 1; off < 64; off <<= 1) ssum += __shfl_xor(ssum, off);
    if (tid == 0) out_b[b] = (m + __logf(ssum)) - s_score;
  }
}

__global__ void reduce_out(const float* __restrict__ in, float* __restrict__ out) {
  float v = in[threadIdx.x];
  for (int off = 1; off < 64; off <<= 1) v += __shfl_xor(v, off);
  if (threadIdx.x == 0) out[0] = v;
}

extern "C" void kernel_launch(void* const* d_in, const int* in_sizes, int n_in,
                              void* d_out, int out_size, void* d_ws, size_t ws_size,
                              hipStream_t stream) {
  const float* sentences = (const float*)d_in[0];
  const int*   labels    = (const int*)  d_in[1];
  const float* w_ih_f    = (const float*)d_in[2];
  const float* w_hh_f    = (const float*)d_in[3];
  const float* b_ih_f    = (const float*)d_in[4];
  const float* b_hh_f    = (const float*)d_in[5];
  const float* w_ih_b    = (const float*)d_in[6];
  const float* w_hh_b    = (const float*)d_in[7];
  const float* b_ih_b    = (const float*)d_in[8];
  const float* b_hh_b    = (const float*)d_in[9];
  const float* fc_w      = (const float*)d_in[10];
  const float* fc_b      = (const float*)d_in[11];
  const float* c_start   = (const float*)d_in[12];
  const float* c_end     = (const float*)d_in[13];
  const float* c_trans   = (const float*)d_in[14];

  char* ws = (char*)d_ws;
  float*  crf_out   = (float*)(ws + CRF_OFF);
  __bf16* xfrag     = (__bf16*)(ws + XF_OFF);
  __bf16* hff       = (__bf16*)(ws + HF_OFF);
  __bf16* hbf       = (__bf16*)(ws + HB_OFF);
  float*  em        = (float*)(ws + EM_OFF);
  __bf16* wfrag     = (__bf16*)(ws + WF_OFF);  // overlaps em (consumed before em written)

  fill_sent<<<4096, 256, 0, stream>>>(hff);    // sentinels both h buffers (64 MiB)
  prep_xfrag<<<4096, 256, 0, stream>>>(sentences, xfrag);
  prep_wfrag<<<1536, 256, 0, stream>>>(w_ih_f, w_hh_f, w_ih_b, w_hh_b, wfrag);
  lstm_rec<<<64, 256, 0, stream>>>(wfrag, b_ih_f, b_hh_f, b_ih_b, b_hh_b,
                                   xfrag, hff, hbf);
  fc_em<<<512, 256, 0, stream>>>(hff, hbf, fc_w, fc_b, labels, em);
  crf_k<<<64, 256, 0, stream>>>(em, labels, c_start, c_end, c_trans, crf_out);
  reduce_out<<<1, 64, 0, stream>>>(crf_out, (float*)d_out);
}